// Round 1
// baseline (240.559 us; speedup 1.0000x reference)
//
#include <hip/hip_runtime.h>

// out[n, t] = sum_{j <= t} W[t, j] * x[n, j] + b[t]
// B = 1048576, T = 32, fp32 in/out. Memory-bound floor: ~256 MB @ ~6.3 TB/s -> ~40 us.
//
// R1 change: W/b moved from LDS broadcasts (528 ds_read_b32 per thread -- the
// measured bottleneck, ~87 us of LDS pipe per CU) to wave-uniform scalar loads
// (s_load -> SGPR operand of v_fma). x row preloaded into 32 VGPRs.

constexpr int T    = 32;
constexpr int ROWS = 256;         // rows per block (== block size: 1 thread per row)
constexpr int RSTR = T + 1;       // padded LDS row stride (33) -> conflict-free row reads

__global__ __launch_bounds__(256) void triu_kernel(
    const float* __restrict__ x, const float* __restrict__ W,
    const float* __restrict__ b, float* __restrict__ out)
{
    __shared__ float sX[ROWS * RSTR];   // 33792 B -> 4 blocks/CU

    const int tid = threadIdx.x;
    const long long base = (long long)blockIdx.x * (ROWS * T);

    // Coalesced float4 staging of the 256x32 input tile into padded LDS.
    const float4* __restrict__ x4 = reinterpret_cast<const float4*>(x + base);
    #pragma unroll
    for (int it = 0; it < (ROWS * T) / (256 * 4); ++it) {   // 8 iters
        const int idx = it * 256 + tid;      // float4 index in tile
        const float4 v = x4[idx];
        const int row = idx >> 3;            // (idx*4)/32
        const int col = (idx & 7) << 2;      // (idx*4)%32
        const int p = row * RSTR + col;
        sX[p + 0] = v.x; sX[p + 1] = v.y; sX[p + 2] = v.z; sX[p + 3] = v.w;
    }
    __syncthreads();

    // Pull this thread's row into registers.
    // bank(tid*33 + j) = (tid + j) % 32: lanes l and l+32 alias 2-way -> free.
    float* myrow = &sX[tid * RSTR];
    float xr[T];
    #pragma unroll
    for (int j = 0; j < T; ++j) xr[j] = myrow[j];

    // Triangular FMA. W[t*T+j] / b[t] are uniform, constant-indexed, __restrict__
    // -> compiler emits s_load (scalar cache), FMA reads the SGPR directly.
    // t-outer keeps W accesses row-contiguous so s_loads merge into dwordx4/x8/x16.
    #pragma unroll
    for (int t = 0; t < T; ++t) {
        float acc = b[t];
        #pragma unroll
        for (int j = 0; j <= t; ++j)
            acc = fmaf(W[t * T + j], xr[j], acc);
        myrow[t] = acc;                  // overwrite own row (no cross-thread hazard)
    }
    __syncthreads();

    // Coalesced float4 stores.
    float4* __restrict__ o4 = reinterpret_cast<float4*>(out + base);
    #pragma unroll
    for (int it = 0; it < 8; ++it) {
        const int idx = it * 256 + tid;
        const int row = idx >> 3;
        const int col = (idx & 7) << 2;
        const int p = row * RSTR + col;
        o4[idx] = make_float4(sX[p + 0], sX[p + 1], sX[p + 2], sX[p + 3]);
    }
}

extern "C" void kernel_launch(void* const* d_in, const int* in_sizes, int n_in,
                              void* d_out, int out_size, void* d_ws, size_t ws_size,
                              hipStream_t stream) {
    const float* x  = (const float*)d_in[0];   // [B, 32]
    const float* W  = (const float*)d_in[1];   // [32, 32] (lower-tri used)
    const float* b  = (const float*)d_in[2];   // [32]
    float* out      = (float*)d_out;           // [B, 32]

    const int batch = in_sizes[0] / T;         // 1048576
    const int grid  = batch / ROWS;            // 4096 blocks
    triu_kernel<<<grid, 256, 0, stream>>>(x, W, b, out);
}